// Round 1
// baseline (2193.836 us; speedup 1.0000x reference)
//
#include <hip/hip_runtime.h>
#include <math.h>

// ---------------------------------------------------------------------------
// Problem constants: B=4, L=2048, D=1024, H=16, Hd=64
// qkv = x @ W_qkv + b_qkv          [8192, 3072]
// attn per (b,h): causal softmax(Q K^T / 8) V   (L=2048, Hd=64)
// out = ctx @ W_lin + b_lin        [8192, 1024]
// ---------------------------------------------------------------------------

#define TM 128
#define TN 128
#define TK 8

// C[M,N] = A[M,K] @ B[K,N] + bias[N]
// 256 threads, 128x128 tile, 8x8 per thread (cols split 4+4 to dodge LDS
// bank conflicts: stride-4 col reads are 2-way = free; stride-8 would be 4-way).
__global__ __launch_bounds__(256) void sgemm_bias(
    const float* __restrict__ A, const float* __restrict__ B,
    const float* __restrict__ bias, float* __restrict__ C,
    int M, int N, int K)
{
    __shared__ float As[TK][TM];   // A tile transposed: As[k][m]
    __shared__ float Bs[TK][TN];

    const int tid = threadIdx.x;
    const int row0 = blockIdx.y * TM;
    const int col0 = blockIdx.x * TN;

    const int tm = tid >> 4;          // 0..15  -> rows tm*8 .. +7
    const int tn = tid & 15;          // 0..15  -> cols tn*4..+3 and 64+tn*4..+3

    // A load: one float4 per thread per K-tile. row=tid/2, k-offset=(tid&1)*4
    const int ar = tid >> 1;
    const int ak = (tid & 1) * 4;
    // B load: one float4 per thread. r8=tid/32, col=(tid&31)*4
    const int br = tid >> 5;
    const int bc = (tid & 31) * 4;

    const float* Ap = A + (size_t)(row0 + ar) * K + ak;
    const float* Bp = B + (size_t)br * N + col0 + bc;

    float acc[8][8];
    #pragma unroll
    for (int i = 0; i < 8; ++i)
        #pragma unroll
        for (int j = 0; j < 8; ++j) acc[i][j] = 0.f;

    for (int kt = 0; kt < K; kt += TK) {
        float4 av = *(const float4*)(Ap + kt);
        float4 bv = *(const float4*)(Bp + (size_t)kt * N);
        As[ak + 0][ar] = av.x;
        As[ak + 1][ar] = av.y;
        As[ak + 2][ar] = av.z;
        As[ak + 3][ar] = av.w;
        *(float4*)&Bs[br][bc] = bv;
        __syncthreads();

        #pragma unroll
        for (int k = 0; k < TK; ++k) {
            float a[8], b[8];
            *(float4*)&a[0] = *(const float4*)&As[k][tm * 8];
            *(float4*)&a[4] = *(const float4*)&As[k][tm * 8 + 4];
            *(float4*)&b[0] = *(const float4*)&Bs[k][tn * 4];
            *(float4*)&b[4] = *(const float4*)&Bs[k][64 + tn * 4];
            #pragma unroll
            for (int i = 0; i < 8; ++i)
                #pragma unroll
                for (int j = 0; j < 8; ++j)
                    acc[i][j] += a[i] * b[j];
        }
        __syncthreads();
    }

    float bia[8];
    #pragma unroll
    for (int j = 0; j < 4; ++j) {
        bia[j]     = bias[col0 + tn * 4 + j];
        bia[j + 4] = bias[col0 + 64 + tn * 4 + j];
    }

    #pragma unroll
    for (int i = 0; i < 8; ++i) {
        const int row = row0 + tm * 8 + i;
        float4 o0, o1;
        o0.x = acc[i][0] + bia[0]; o0.y = acc[i][1] + bia[1];
        o0.z = acc[i][2] + bia[2]; o0.w = acc[i][3] + bia[3];
        o1.x = acc[i][4] + bia[4]; o1.y = acc[i][5] + bia[5];
        o1.z = acc[i][6] + bia[6]; o1.w = acc[i][7] + bia[7];
        *(float4*)(C + (size_t)row * N + col0 + tn * 4)      = o0;
        *(float4*)(C + (size_t)row * N + col0 + 64 + tn * 4) = o1;
    }
}

// ---------------------------------------------------------------------------
// Flash-style causal attention, fp32.
// Grid: (L/64, H, B). Block: 256 threads. Each block does a 64-row Q tile.
// Thread (r, cq): r = tid/4 owns score row r, cq = tid&3 owns 16 cols of S
// and 16 dims of ctx. Row stats reduced over the 4 cq-lanes via shfl_xor.
// K is stored transposed (Kt[d][c]) so QK^T reads are contiguous b128.
// ---------------------------------------------------------------------------
__global__ __launch_bounds__(256) void flash_attn_f32(
    const float* __restrict__ qkv, float* __restrict__ ctx)
{
    const int L = 2048, D3 = 3072, D = 1024;
    const int qt = blockIdx.x;   // 0..31
    const int h  = blockIdx.y;   // 0..15
    const int b  = blockIdx.z;   // 0..3
    const int q0 = qt * 64;

    const float* base = qkv + (size_t)b * L * D3;
    const int qoff = h * 64;
    const int koff = 1024 + h * 64;
    const int voff = 2048 + h * 64;

    __shared__ float Qs[64][68];   // scaled Q, row-major
    __shared__ float Kt[64][68];   // Kt[d][c] = K[c][d]
    __shared__ float Vs[64][68];   // row-major V
    __shared__ float Ps[64][68];   // P tile

    const int tid = threadIdx.x;
    const int r  = tid >> 2;   // 0..63
    const int cq = tid & 3;    // 0..3

    // Load + scale Q tile (softmax scale 1/sqrt(64) folded into Q).
    for (int i = tid; i < 64 * 16; i += 256) {
        const int rr = i >> 4, c4 = (i & 15) * 4;
        float4 v = *(const float4*)(base + (size_t)(q0 + rr) * D3 + qoff + c4);
        Qs[rr][c4 + 0] = v.x * 0.125f;
        Qs[rr][c4 + 1] = v.y * 0.125f;
        Qs[rr][c4 + 2] = v.z * 0.125f;
        Qs[rr][c4 + 3] = v.w * 0.125f;
    }

    float m = -INFINITY, l = 0.f;
    float acc[16];
    #pragma unroll
    for (int j = 0; j < 16; ++j) acc[j] = 0.f;

    __syncthreads();

    for (int kt = 0; kt <= qt; ++kt) {
        const int k0 = kt * 64;
        // Stage K (transposed) and V.
        for (int i = tid; i < 64 * 16; i += 256) {
            const int rr = i >> 4, c4 = (i & 15) * 4;
            const float* kp = base + (size_t)(k0 + rr) * D3 + koff + c4;
            float4 kv = *(const float4*)kp;
            Kt[c4 + 0][rr] = kv.x;
            Kt[c4 + 1][rr] = kv.y;
            Kt[c4 + 2][rr] = kv.z;
            Kt[c4 + 3][rr] = kv.w;
            float4 vv = *(const float4*)(base + (size_t)(k0 + rr) * D3 + voff + c4);
            *(float4*)&Vs[rr][c4] = vv;
        }
        __syncthreads();

        // S row r, cols cq*16 .. +15
        float s[16];
        #pragma unroll
        for (int j = 0; j < 16; ++j) s[j] = 0.f;
        for (int d4 = 0; d4 < 16; ++d4) {
            float4 q4 = *(const float4*)&Qs[r][d4 * 4];
            const float qc[4] = {q4.x, q4.y, q4.z, q4.w};
            #pragma unroll
            for (int dd = 0; dd < 4; ++dd) {
                const float q = qc[dd];
                const int d = d4 * 4 + dd;
                #pragma unroll
                for (int j4 = 0; j4 < 4; ++j4) {
                    float4 kv = *(const float4*)&Kt[d][cq * 16 + j4 * 4];
                    s[j4 * 4 + 0] += q * kv.x;
                    s[j4 * 4 + 1] += q * kv.y;
                    s[j4 * 4 + 2] += q * kv.z;
                    s[j4 * 4 + 3] += q * kv.w;
                }
            }
        }

        if (kt == qt) {   // causal mask on the diagonal tile (k0 == q0)
            #pragma unroll
            for (int j = 0; j < 16; ++j)
                if (cq * 16 + j > r) s[j] = -INFINITY;
        }

        // Online softmax (row stats across the 4 cq lanes).
        float tmax = s[0];
        #pragma unroll
        for (int j = 1; j < 16; ++j) tmax = fmaxf(tmax, s[j]);
        tmax = fmaxf(tmax, __shfl_xor(tmax, 1, 4));
        tmax = fmaxf(tmax, __shfl_xor(tmax, 2, 4));
        const float mn = fmaxf(m, tmax);
        const float alpha = __expf(m - mn);   // exp(-inf)=0 on first tile
        float psum = 0.f;
        #pragma unroll
        for (int j = 0; j < 16; ++j) {
            const float p = __expf(s[j] - mn);
            Ps[r][cq * 16 + j] = p;
            psum += p;
        }
        psum += __shfl_xor(psum, 1, 4);
        psum += __shfl_xor(psum, 2, 4);
        l = l * alpha + psum;
        m = mn;
        #pragma unroll
        for (int j = 0; j < 16; ++j) acc[j] *= alpha;

        // PV: same-wave Ps producer/consumer (rows disjoint per wave), no
        // barrier needed — compiler orders the LDS ops.
        for (int c = 0; c < 64; ++c) {
            const float p = Ps[r][c];
            #pragma unroll
            for (int j4 = 0; j4 < 4; ++j4) {
                float4 vv = *(const float4*)&Vs[c][cq * 16 + j4 * 4];
                acc[j4 * 4 + 0] += p * vv.x;
                acc[j4 * 4 + 1] += p * vv.y;
                acc[j4 * 4 + 2] += p * vv.z;
                acc[j4 * 4 + 3] += p * vv.w;
            }
        }
        __syncthreads();   // all lanes done with Kt/Vs before next stage
    }

    const float inv = 1.f / l;
    float* outp = ctx + ((size_t)(b * L + q0 + r)) * D + h * 64 + cq * 16;
    #pragma unroll
    for (int j4 = 0; j4 < 4; ++j4) {
        float4 o;
        o.x = acc[j4 * 4 + 0] * inv;
        o.y = acc[j4 * 4 + 1] * inv;
        o.z = acc[j4 * 4 + 2] * inv;
        o.w = acc[j4 * 4 + 3] * inv;
        *(float4*)(outp + j4 * 4) = o;
    }
}

extern "C" void kernel_launch(void* const* d_in, const int* in_sizes, int n_in,
                              void* d_out, int out_size, void* d_ws, size_t ws_size,
                              hipStream_t stream) {
    const float* x     = (const float*)d_in[0];
    const float* W_qkv = (const float*)d_in[1];
    const float* b_qkv = (const float*)d_in[2];
    const float* W_lin = (const float*)d_in[3];
    const float* b_lin = (const float*)d_in[4];
    float* out = (float*)d_out;

    const int M = 8192;     // B*L
    const int D = 1024, D3 = 3072;

    float* qkvbuf = (float*)d_ws;                    // [8192, 3072] = 96 MiB
    float* ctxbuf = qkvbuf + (size_t)M * D3;         // [8192, 1024] = 32 MiB

    // 1) QKV projection
    sgemm_bias<<<dim3(D3 / TN, M / TM), 256, 0, stream>>>(
        x, W_qkv, b_qkv, qkvbuf, M, D3, D);
    // 2) causal attention -> ctx (already merged heads: [B, L, D])
    flash_attn_f32<<<dim3(32, 16, 4), 256, 0, stream>>>(qkvbuf, ctxbuf);
    // 3) output projection
    sgemm_bias<<<dim3(D / TN, M / TM), 256, 0, stream>>>(
        ctxbuf, W_lin, b_lin, out, M, D, D);
}

// Round 3
// 1356.108 us; speedup vs baseline: 1.6177x; 1.6177x over previous
//
#include <hip/hip_runtime.h>
#include <math.h>

// ---------------------------------------------------------------------------
// B=4, L=2048, D=1024, H=16, Hd=64
// qkv = x @ W_qkv + b_qkv          [8192, 3072]   (fp32 VALU GEMM)
// attn per (b,h): causal softmax(Q K^T / 8) V     (bf16-split MFMA)
// out = ctx @ W_lin + b_lin        [8192, 1024]   (fp32 VALU GEMM)
// ---------------------------------------------------------------------------

#define TM 128
#define TN 128
#define TK 8

typedef __attribute__((ext_vector_type(8))) short bf16x8;
typedef __attribute__((ext_vector_type(4))) float f32x4;

#define MFMA16(a, b, c) __builtin_amdgcn_mfma_f32_16x16x32_bf16(a, b, c, 0, 0, 0)

// Split fp32 into bf16 hi + bf16 lo (truncation; x ~= hi + lo, residual ~2^-16 rel)
__device__ __forceinline__ void bsplit(float x, short& hi, short& lo) {
    unsigned u = __builtin_bit_cast(unsigned, x);
    unsigned hu = u & 0xffff0000u;
    hi = (short)(hu >> 16);
    float r = x - __builtin_bit_cast(float, hu);
    lo = (short)(__builtin_bit_cast(unsigned, r) >> 16);
}

// LDS XOR swizzle for 64x64 bf16 tiles (stride 128 B): XOR short-index bits 3-5
// with row&7. Keeps 16B alignment for b128 fragment reads; all fragment-read
// patterns become <=2-way bank aliasing (free).
__device__ __forceinline__ int swz(int row, int col) {
    return ((row << 6) | col) ^ ((row & 7) << 3);
}

// ---------------------------------------------------------------------------
// fp32 GEMM, unchanged from round 1 (95 TF combined; next round's target).
// ---------------------------------------------------------------------------
__global__ __launch_bounds__(256) void sgemm_bias(
    const float* __restrict__ A, const float* __restrict__ B,
    const float* __restrict__ bias, float* __restrict__ C,
    int M, int N, int K)
{
    __shared__ float As[TK][TM];
    __shared__ float Bs[TK][TN];

    const int tid = threadIdx.x;
    const int row0 = blockIdx.y * TM;
    const int col0 = blockIdx.x * TN;

    const int tm = tid >> 4;
    const int tn = tid & 15;

    const int ar = tid >> 1;
    const int ak = (tid & 1) * 4;
    const int br = tid >> 5;
    const int bc = (tid & 31) * 4;

    const float* Ap = A + (size_t)(row0 + ar) * K + ak;
    const float* Bp = B + (size_t)br * N + col0 + bc;

    float acc[8][8];
    #pragma unroll
    for (int i = 0; i < 8; ++i)
        #pragma unroll
        for (int j = 0; j < 8; ++j) acc[i][j] = 0.f;

    for (int kt = 0; kt < K; kt += TK) {
        float4 av = *(const float4*)(Ap + kt);
        float4 bv = *(const float4*)(Bp + (size_t)kt * N);
        As[ak + 0][ar] = av.x;
        As[ak + 1][ar] = av.y;
        As[ak + 2][ar] = av.z;
        As[ak + 3][ar] = av.w;
        *(float4*)&Bs[br][bc] = bv;
        __syncthreads();

        #pragma unroll
        for (int k = 0; k < TK; ++k) {
            float a[8], b[8];
            *(float4*)&a[0] = *(const float4*)&As[k][tm * 8];
            *(float4*)&a[4] = *(const float4*)&As[k][tm * 8 + 4];
            *(float4*)&b[0] = *(const float4*)&Bs[k][tn * 4];
            *(float4*)&b[4] = *(const float4*)&Bs[k][64 + tn * 4];
            #pragma unroll
            for (int i = 0; i < 8; ++i)
                #pragma unroll
                for (int j = 0; j < 8; ++j)
                    acc[i][j] += a[i] * b[j];
        }
        __syncthreads();
    }

    float bia[8];
    #pragma unroll
    for (int j = 0; j < 4; ++j) {
        bia[j]     = bias[col0 + tn * 4 + j];
        bia[j + 4] = bias[col0 + 64 + tn * 4 + j];
    }

    #pragma unroll
    for (int i = 0; i < 8; ++i) {
        const int row = row0 + tm * 8 + i;
        float4 o0, o1;
        o0.x = acc[i][0] + bia[0]; o0.y = acc[i][1] + bia[1];
        o0.z = acc[i][2] + bia[2]; o0.w = acc[i][3] + bia[3];
        o1.x = acc[i][4] + bia[4]; o1.y = acc[i][5] + bia[5];
        o1.z = acc[i][6] + bia[6]; o1.w = acc[i][7] + bia[7];
        *(float4*)(C + (size_t)row * N + col0 + tn * 4)      = o0;
        *(float4*)(C + (size_t)row * N + col0 + 64 + tn * 4) = o1;
    }
}

// ---------------------------------------------------------------------------
// Flash attention with bf16-split MFMA (fp32-equivalent precision).
// Grid (32, 16, 4); block 256 = 4 waves; each wave owns 16 Q rows.
// A-frag layout (16x16x32): row = lane&15, k = (lane>>4)*8 + e
// B-frag layout:            col = lane&15, k = (lane>>4)*8 + e
// C/D layout (m89-verified): col = lane&15, row = (lane>>4)*4 + reg
// ---------------------------------------------------------------------------
__global__ __launch_bounds__(256) void attn_mfma(
    const float* __restrict__ qkv, float* __restrict__ ctx)
{
    const int L = 2048, D3 = 3072, D = 1024;
    const int qt = blockIdx.x;
    const int h  = blockIdx.y;
    const int b  = blockIdx.z;
    const int q0 = qt * 64;

    const float* base = qkv + (size_t)b * L * D3;
    const int koff = 1024 + h * 64;
    const int voff = 2048 + h * 64;

    __shared__ short K_hi[64 * 64], K_lo[64 * 64];   // [key][d]   swizzled
    __shared__ short Vt_hi[64 * 64], Vt_lo[64 * 64]; // [d][key]   swizzled
    __shared__ short P_hi[64 * 64], P_lo[64 * 64];   // [qrow][key] swizzled

    const int tid = threadIdx.x;
    const int w = tid >> 6;        // wave 0..3 -> Q rows w*16..+15
    const int lane = tid & 63;
    const int ln = lane & 15;
    const int lg = lane >> 4;      // 0..3

    // Q A-fragments in registers, softmax scale 1/8 folded in.
    bf16x8 qa_hi[2], qa_lo[2];
    {
        const float* qp = base + (size_t)(q0 + w * 16 + ln) * D3 + h * 64 + lg * 8;
        #pragma unroll
        for (int ks = 0; ks < 2; ++ks) {
            float4 f0 = *(const float4*)(qp + ks * 32);
            float4 f1 = *(const float4*)(qp + ks * 32 + 4);
            float v[8] = {f0.x, f0.y, f0.z, f0.w, f1.x, f1.y, f1.z, f1.w};
            #pragma unroll
            for (int e = 0; e < 8; ++e) {
                short hi, lo;
                bsplit(v[e] * 0.125f, hi, lo);
                qa_hi[ks][e] = hi;
                qa_lo[ks][e] = lo;
            }
        }
    }

    float m[4], lsum[4];
    f32x4 acc[4];
    #pragma unroll
    for (int r = 0; r < 4; ++r) { m[r] = -INFINITY; lsum[r] = 0.f; }
    #pragma unroll
    for (int n = 0; n < 4; ++n) acc[n] = (f32x4){0.f, 0.f, 0.f, 0.f};

    for (int kt = 0; kt <= qt; ++kt) {
        const int k0 = kt * 64;
        __syncthreads();   // previous iteration's K/Vt reads are done

        // Stage K (row-major) and V (transposed) as bf16 hi/lo, swizzled.
        for (int i = tid; i < 64 * 16; i += 256) {
            const int rr = i >> 4, c4 = (i & 15) * 4;
            const float* rowp = base + (size_t)(k0 + rr) * D3;
            float4 kv = *(const float4*)(rowp + koff + c4);
            float4 vv = *(const float4*)(rowp + voff + c4);
            float kk[4] = {kv.x, kv.y, kv.z, kv.w};
            float vf[4] = {vv.x, vv.y, vv.z, vv.w};
            short kh[4], kl[4];
            #pragma unroll
            for (int j = 0; j < 4; ++j) {
                bsplit(kk[j], kh[j], kl[j]);
                short vh, vl;
                bsplit(vf[j], vh, vl);
                Vt_hi[swz(c4 + j, rr)] = vh;   // transposed scatter (swizzle-spread)
                Vt_lo[swz(c4 + j, rr)] = vl;
            }
            const int si = swz(rr, c4);        // 8B-aligned packed store
            *(uint2*)&K_hi[si] = make_uint2(
                (unsigned)(unsigned short)kh[0] | ((unsigned)(unsigned short)kh[1] << 16),
                (unsigned)(unsigned short)kh[2] | ((unsigned)(unsigned short)kh[3] << 16));
            *(uint2*)&K_lo[si] = make_uint2(
                (unsigned)(unsigned short)kl[0] | ((unsigned)(unsigned short)kl[1] << 16),
                (unsigned)(unsigned short)kl[2] | ((unsigned)(unsigned short)kl[3] << 16));
        }
        __syncthreads();

        // S = Q K^T : 4 col-fragments x 2 k-steps x 3 split-terms = 24 MFMAs
        f32x4 s[4];
        #pragma unroll
        for (int n = 0; n < 4; ++n) {
            f32x4 sa = (f32x4){0.f, 0.f, 0.f, 0.f};
            #pragma unroll
            for (int ks = 0; ks < 2; ++ks) {
                bf16x8 kb_hi = *(const bf16x8*)&K_hi[swz(n * 16 + ln, ks * 32 + lg * 8)];
                bf16x8 kb_lo = *(const bf16x8*)&K_lo[swz(n * 16 + ln, ks * 32 + lg * 8)];
                sa = MFMA16(qa_hi[ks], kb_hi, sa);
                sa = MFMA16(qa_lo[ks], kb_hi, sa);
                sa = MFMA16(qa_hi[ks], kb_lo, sa);
            }
            s[n] = sa;
        }

        // Causal mask (diagonal tile only: k0 == q0).
        if (kt == qt) {
            #pragma unroll
            for (int n = 0; n < 4; ++n)
                #pragma unroll
                for (int r = 0; r < 4; ++r) {
                    const int key = n * 16 + ln;
                    const int qr  = w * 16 + lg * 4 + r;
                    if (key > qr) s[n][r] = -INFINITY;
                }
        }

        // Online softmax; row r of this lane = w*16 + lg*4 + r, reduced over
        // the 16 lanes (bits 0..3) that share lg.
        float al[4];
        #pragma unroll
        for (int r = 0; r < 4; ++r) {
            float t = fmaxf(fmaxf(s[0][r], s[1][r]), fmaxf(s[2][r], s[3][r]));
            t = fmaxf(t, __shfl_xor(t, 1));
            t = fmaxf(t, __shfl_xor(t, 2));
            t = fmaxf(t, __shfl_xor(t, 4));
            t = fmaxf(t, __shfl_xor(t, 8));
            const float mn = fmaxf(m[r], t);
            al[r] = __expf(m[r] - mn);   // exp(-inf)=0 on first tile
            m[r] = mn;
        }

        float ps[4] = {0.f, 0.f, 0.f, 0.f};
        #pragma unroll
        for (int n = 0; n < 4; ++n) {
            #pragma unroll
            for (int r = 0; r < 4; ++r) {
                const float p = __expf(s[n][r] - m[r]);
                ps[r] += p;
                short ph, pl;
                bsplit(p, ph, pl);
                const int row = w * 16 + lg * 4 + r;
                const int key = n * 16 + ln;
                P_hi[swz(row, key)] = ph;
                P_lo[swz(row, key)] = pl;
            }
        }
        #pragma unroll
        for (int r = 0; r < 4; ++r) {
            float t = ps[r];
            t += __shfl_xor(t, 1);
            t += __shfl_xor(t, 2);
            t += __shfl_xor(t, 4);
            t += __shfl_xor(t, 8);
            lsum[r] = lsum[r] * al[r] + t;
            acc[0][r] *= al[r];
            acc[1][r] *= al[r];
            acc[2][r] *= al[r];
            acc[3][r] *= al[r];
        }

        // PV: A = P (wave-local LDS round trip, no barrier needed), B = Vt.
        bf16x8 pa_hi[2], pa_lo[2];
        #pragma unroll
        for (int ks = 0; ks < 2; ++ks) {
            pa_hi[ks] = *(const bf16x8*)&P_hi[swz(w * 16 + ln, ks * 32 + lg * 8)];
            pa_lo[ks] = *(const bf16x8*)&P_lo[swz(w * 16 + ln, ks * 32 + lg * 8)];
        }
        #pragma unroll
        for (int n = 0; n < 4; ++n) {
            #pragma unroll
            for (int ks = 0; ks < 2; ++ks) {
                bf16x8 vb_hi = *(const bf16x8*)&Vt_hi[swz(n * 16 + ln, ks * 32 + lg * 8)];
                bf16x8 vb_lo = *(const bf16x8*)&Vt_lo[swz(n * 16 + ln, ks * 32 + lg * 8)];
                acc[n] = MFMA16(pa_hi[ks], vb_hi, acc[n]);
                acc[n] = MFMA16(pa_lo[ks], vb_hi, acc[n]);
                acc[n] = MFMA16(pa_hi[ks], vb_lo, acc[n]);
            }
        }
    }

    #pragma unroll
    for (int r = 0; r < 4; ++r) {
        const float inv = 1.f / lsum[r];
        const int q = q0 + w * 16 + lg * 4 + r;
        float* op = ctx + ((size_t)(b * L) + q) * D + h * 64;
        #pragma unroll
        for (int n = 0; n < 4; ++n)
            op[n * 16 + ln] = acc[n][r] * inv;
    }
}

extern "C" void kernel_launch(void* const* d_in, const int* in_sizes, int n_in,
                              void* d_out, int out_size, void* d_ws, size_t ws_size,
                              hipStream_t stream) {
    const float* x     = (const float*)d_in[0];
    const float* W_qkv = (const float*)d_in[1];
    const float* b_qkv = (const float*)d_in[2];
    const float* W_lin = (const float*)d_in[3];
    const float* b_lin = (const float*)d_in[4];
    float* out = (float*)d_out;

    const int M = 8192;
    const int D = 1024, D3 = 3072;

    float* qkvbuf = (float*)d_ws;                // [8192, 3072] = 96 MiB
    float* ctxbuf = qkvbuf + (size_t)M * D3;     // [8192, 1024] = 32 MiB

    sgemm_bias<<<dim3(D3 / TN, M / TM), 256, 0, stream>>>(
        x, W_qkv, b_qkv, qkvbuf, M, D3, D);
    attn_mfma<<<dim3(32, 16, 4), 256, 0, stream>>>(qkvbuf, ctxbuf);
    sgemm_bias<<<dim3(D / TN, M / TM), 256, 0, stream>>>(
        ctxbuf, W_lin, b_lin, out, M, D, D);
}

// Round 5
// 801.634 us; speedup vs baseline: 2.7367x; 1.6917x over previous
//
#include <hip/hip_runtime.h>
#include <math.h>
#include <stdint.h>

// ---------------------------------------------------------------------------
// B=4, L=2048, D=1024, H=16, Hd=64
// 1) wsplit_t: W_qkv -> W^T bf16 hi/lo            (k-contiguous for MFMA frags)
// 2) gemm_split<true>:  qkv = x @ W_qkv + b       (bf16-split MFMA, A=f32 regstage)
// 3) attn_mfma: causal flash attn                 (bf16-split MFMA, ctx -> hi/lo)
// 4) wsplit_t: W_lin -> W^T bf16 hi/lo            (into dead qkv region)
// 5) gemm_split<false>: out = ctx @ W_lin + b     (all streams global_load_lds)
//
// ws layout (128 MiB, proven available):
//   [0,96M)    qkv f32;  after attn: first 4M = Wlin^T hi/lo
//   [96M,128M) ctx hi/lo (16M+16M); before attn: Wqkv^T hi/lo (6M+6M) aliased
// ---------------------------------------------------------------------------

typedef __attribute__((ext_vector_type(8))) short bf16x8;
typedef __attribute__((ext_vector_type(4))) float f32x4;
typedef unsigned short u16;

#define MFMA16(a, b, c) __builtin_amdgcn_mfma_f32_16x16x32_bf16(a, b, c, 0, 0, 0)

// Split fp32 into bf16 hi + bf16 lo (x ~= hi + lo, residual ~2^-16 rel)
__device__ __forceinline__ void bsplit(float x, short& hi, short& lo) {
    unsigned u = __builtin_bit_cast(unsigned, x);
    unsigned hu = u & 0xffff0000u;
    hi = (short)(hu >> 16);
    float r = x - __builtin_bit_cast(float, hu);
    lo = (short)(__builtin_bit_cast(unsigned, r) >> 16);
}

// async global->LDS, 16B per lane
__device__ __forceinline__ void gload16(const void* g, void* l) {
    __builtin_amdgcn_global_load_lds(
        (const __attribute__((address_space(1))) void*)g,
        (__attribute__((address_space(3))) void*)l, 16, 0, 0);
}

// LDS XOR swizzle used by the attention kernel (64x64 bf16 tiles)
__device__ __forceinline__ int swz(int row, int col) {
    return ((row << 6) | col) ^ ((row & 7) << 3);
}

// ---------------------------------------------------------------------------
// Transpose + split: W[K][N] f32 -> outh/outl[N][K] bf16
// ---------------------------------------------------------------------------
__global__ __launch_bounds__(256) void wsplit_t(
    const float* __restrict__ W, u16* __restrict__ outh, u16* __restrict__ outl,
    int K, int N)
{
    __shared__ float t[64][68];
    const int n0 = blockIdx.x * 64, k0 = blockIdx.y * 64;
    const int tid = threadIdx.x;
    const int r = tid >> 4, c4 = (tid & 15) * 4;
    #pragma unroll
    for (int i = 0; i < 4; ++i) {
        const int rr = r + i * 16;
        float4 v = *(const float4*)&W[(size_t)(k0 + rr) * N + n0 + c4];
        t[rr][c4 + 0] = v.x; t[rr][c4 + 1] = v.y;
        t[rr][c4 + 2] = v.z; t[rr][c4 + 3] = v.w;
    }
    __syncthreads();
    #pragma unroll
    for (int i = 0; i < 4; ++i) {
        const int nr = r + i * 16;
        unsigned h01 = 0, h23 = 0, l01 = 0, l23 = 0;
        {
            short hh, ll;
            bsplit(t[c4 + 0][nr], hh, ll); h01 |= (unsigned)(u16)hh; l01 |= (unsigned)(u16)ll;
            bsplit(t[c4 + 1][nr], hh, ll); h01 |= (unsigned)(u16)hh << 16; l01 |= (unsigned)(u16)ll << 16;
            bsplit(t[c4 + 2][nr], hh, ll); h23 |= (unsigned)(u16)hh; l23 |= (unsigned)(u16)ll;
            bsplit(t[c4 + 3][nr], hh, ll); h23 |= (unsigned)(u16)hh << 16; l23 |= (unsigned)(u16)ll << 16;
        }
        *(uint2*)&outh[(size_t)(n0 + nr) * K + k0 + c4] = make_uint2(h01, h23);
        *(uint2*)&outl[(size_t)(n0 + nr) * K + k0 + c4] = make_uint2(l01, l23);
    }
}

// ---------------------------------------------------------------------------
// bf16-split MFMA GEMM: C[M,N] = A @ B^T' + bias, fp32-equivalent precision.
// B given transposed-split: Bth/Btl[N][K]. A either f32 [M][K] (AF32, reg-
// staged + split) or pre-split Ah/Al[M][K] (global_load_lds).
// 128x128 tile, BK=32, 256 thr = 4 waves (2x2 of 64x64), m97 2-barrier loop.
// ---------------------------------------------------------------------------
template<bool AF32>
__global__ __launch_bounds__(256) void gemm_split(
    const float* __restrict__ Af,
    const u16* __restrict__ Ah, const u16* __restrict__ Al,
    const u16* __restrict__ Bth, const u16* __restrict__ Btl,
    const float* __restrict__ bias, float* __restrict__ C,
    int M, int N, int K)
{
    __shared__ u16 sAh[128 * 32], sAl[128 * 32], sBh[128 * 32], sBl[128 * 32];

    const int tid  = threadIdx.x;
    const int lane = tid & 63;
    const int ln   = lane & 15;
    const int lg   = lane >> 4;
    const int w    = tid >> 6;
    const int wr   = (w >> 1) * 64;
    const int wc   = (w & 1) * 64;
    const int row0 = blockIdx.y * 128;
    const int col0 = blockIdx.x * 128;

    f32x4 acc[4][4];
    #pragma unroll
    for (int mi = 0; mi < 4; ++mi)
        #pragma unroll
        for (int ni = 0; ni < 4; ++ni)
            acc[mi][ni] = (f32x4){0.f, 0.f, 0.f, 0.f};

    for (int kt = 0; kt < K; kt += 32) {
        __syncthreads();
        #pragma unroll
        for (int rd = 0; rd < 2; ++rd) {
            const int ch = tid + rd * 256;          // 512 16B-chunks per stream
            const int r = ch >> 2, kc = (ch & 3) * 8;
            gload16(Bth + (size_t)(col0 + r) * K + kt + kc, &sBh[ch * 8]);
            gload16(Btl + (size_t)(col0 + r) * K + kt + kc, &sBl[ch * 8]);
            if constexpr (!AF32) {
                gload16(Ah + (size_t)(row0 + r) * K + kt + kc, &sAh[ch * 8]);
                gload16(Al + (size_t)(row0 + r) * K + kt + kc, &sAl[ch * 8]);
            }
        }
        if constexpr (AF32) {
            const int r = tid >> 1, ks = (tid & 1) * 16;
            const float* ap = Af + (size_t)(row0 + r) * K + kt + ks;
            float v[16];
            *(float4*)&v[0]  = *(const float4*)(ap + 0);
            *(float4*)&v[4]  = *(const float4*)(ap + 4);
            *(float4*)&v[8]  = *(const float4*)(ap + 8);
            *(float4*)&v[12] = *(const float4*)(ap + 12);
            bf16x8 h0, h1, l0, l1;
            #pragma unroll
            for (int e = 0; e < 8; ++e) {
                short hh, ll;
                bsplit(v[e], hh, ll);     h0[e] = hh; l0[e] = ll;
                bsplit(v[8 + e], hh, ll); h1[e] = hh; l1[e] = ll;
            }
            *(bf16x8*)&sAh[r * 32 + ks]     = h0;
            *(bf16x8*)&sAh[r * 32 + ks + 8] = h1;
            *(bf16x8*)&sAl[r * 32 + ks]     = l0;
            *(bf16x8*)&sAl[r * 32 + ks + 8] = l1;
        }
        __syncthreads();

        bf16x8 a_h[4], a_l[4], b_h[4], b_l[4];
        #pragma unroll
        for (int mi = 0; mi < 4; ++mi) {
            const int o = (wr + mi * 16 + ln) * 32 + lg * 8;
            a_h[mi] = *(const bf16x8*)&sAh[o];
            a_l[mi] = *(const bf16x8*)&sAl[o];
        }
        #pragma unroll
        for (int ni = 0; ni < 4; ++ni) {
            const int o = (wc + ni * 16 + ln) * 32 + lg * 8;
            b_h[ni] = *(const bf16x8*)&sBh[o];
            b_l[ni] = *(const bf16x8*)&sBl[o];
        }
        #pragma unroll
        for (int mi = 0; mi < 4; ++mi)
            #pragma unroll
            for (int ni = 0; ni < 4; ++ni) {
                acc[mi][ni] = MFMA16(a_h[mi], b_h[ni], acc[mi][ni]);
                acc[mi][ni] = MFMA16(a_l[mi], b_h[ni], acc[mi][ni]);
                acc[mi][ni] = MFMA16(a_h[mi], b_l[ni], acc[mi][ni]);
            }
    }

    #pragma unroll
    for (int ni = 0; ni < 4; ++ni) {
        const int col = col0 + wc + ni * 16 + ln;
        const float bi = bias[col];
        #pragma unroll
        for (int mi = 0; mi < 4; ++mi)
            #pragma unroll
            for (int j = 0; j < 4; ++j) {
                const int row = row0 + wr + mi * 16 + lg * 4 + j;
                C[(size_t)row * N + col] = acc[mi][ni][j] + bi;
            }
    }
}

// ---------------------------------------------------------------------------
// Flash attention, bf16-split MFMA (unchanged core from round 3; epilogue now
// writes ctx as bf16 hi/lo so GEMM2 can async-stage it).
// ---------------------------------------------------------------------------
__global__ __launch_bounds__(256) void attn_mfma(
    const float* __restrict__ qkv, u16* __restrict__ ctxh, u16* __restrict__ ctxl)
{
    const int L = 2048, D3 = 3072, D = 1024;
    const int qt = blockIdx.x;
    const int h  = blockIdx.y;
    const int b  = blockIdx.z;
    const int q0 = qt * 64;

    const float* base = qkv + (size_t)b * L * D3;
    const int koff = 1024 + h * 64;
    const int voff = 2048 + h * 64;

    __shared__ short K_hi[64 * 64], K_lo[64 * 64];
    __shared__ short Vt_hi[64 * 64], Vt_lo[64 * 64];
    __shared__ short P_hi[64 * 64], P_lo[64 * 64];

    const int tid = threadIdx.x;
    const int w = tid >> 6;
    const int lane = tid & 63;
    const int ln = lane & 15;
    const int lg = lane >> 4;

    bf16x8 qa_hi[2], qa_lo[2];
    {
        const float* qp = base + (size_t)(q0 + w * 16 + ln) * D3 + h * 64 + lg * 8;
        #pragma unroll
        for (int ks = 0; ks < 2; ++ks) {
            float4 f0 = *(const float4*)(qp + ks * 32);
            float4 f1 = *(const float4*)(qp + ks * 32 + 4);
            float v[8] = {f0.x, f0.y, f0.z, f0.w, f1.x, f1.y, f1.z, f1.w};
            #pragma unroll
            for (int e = 0; e < 8; ++e) {
                short hi, lo;
                bsplit(v[e] * 0.125f, hi, lo);
                qa_hi[ks][e] = hi;
                qa_lo[ks][e] = lo;
            }
        }
    }

    float m[4], lsum[4];
    f32x4 acc[4];
    #pragma unroll
    for (int r = 0; r < 4; ++r) { m[r] = -INFINITY; lsum[r] = 0.f; }
    #pragma unroll
    for (int n = 0; n < 4; ++n) acc[n] = (f32x4){0.f, 0.f, 0.f, 0.f};

    for (int kt = 0; kt <= qt; ++kt) {
        const int k0 = kt * 64;
        __syncthreads();

        for (int i = tid; i < 64 * 16; i += 256) {
            const int rr = i >> 4, c4 = (i & 15) * 4;
            const float* rowp = base + (size_t)(k0 + rr) * D3;
            float4 kv = *(const float4*)(rowp + koff + c4);
            float4 vv = *(const float4*)(rowp + voff + c4);
            float kk[4] = {kv.x, kv.y, kv.z, kv.w};
            float vf[4] = {vv.x, vv.y, vv.z, vv.w};
            short kh[4], kl[4];
            #pragma unroll
            for (int j = 0; j < 4; ++j) {
                bsplit(kk[j], kh[j], kl[j]);
                short vh, vl;
                bsplit(vf[j], vh, vl);
                Vt_hi[swz(c4 + j, rr)] = vh;
                Vt_lo[swz(c4 + j, rr)] = vl;
            }
            const int si = swz(rr, c4);
            *(uint2*)&K_hi[si] = make_uint2(
                (unsigned)(u16)kh[0] | ((unsigned)(u16)kh[1] << 16),
                (unsigned)(u16)kh[2] | ((unsigned)(u16)kh[3] << 16));
            *(uint2*)&K_lo[si] = make_uint2(
                (unsigned)(u16)kl[0] | ((unsigned)(u16)kl[1] << 16),
                (unsigned)(u16)kl[2] | ((unsigned)(u16)kl[3] << 16));
        }
        __syncthreads();

        f32x4 s[4];
        #pragma unroll
        for (int n = 0; n < 4; ++n) {
            f32x4 sa = (f32x4){0.f, 0.f, 0.f, 0.f};
            #pragma unroll
            for (int ks = 0; ks < 2; ++ks) {
                bf16x8 kb_hi = *(const bf16x8*)&K_hi[swz(n * 16 + ln, ks * 32 + lg * 8)];
                bf16x8 kb_lo = *(const bf16x8*)&K_lo[swz(n * 16 + ln, ks * 32 + lg * 8)];
                sa = MFMA16(qa_hi[ks], kb_hi, sa);
                sa = MFMA16(qa_lo[ks], kb_hi, sa);
                sa = MFMA16(qa_hi[ks], kb_lo, sa);
            }
            s[n] = sa;
        }

        if (kt == qt) {
            #pragma unroll
            for (int n = 0; n < 4; ++n)
                #pragma unroll
                for (int r = 0; r < 4; ++r) {
                    const int key = n * 16 + ln;
                    const int qr  = w * 16 + lg * 4 + r;
                    if (key > qr) s[n][r] = -INFINITY;
                }
        }

        float al[4];
        #pragma unroll
        for (int r = 0; r < 4; ++r) {
            float t = fmaxf(fmaxf(s[0][r], s[1][r]), fmaxf(s[2][r], s[3][r]));
            t = fmaxf(t, __shfl_xor(t, 1));
            t = fmaxf(t, __shfl_xor(t, 2));
            t = fmaxf(t, __shfl_xor(t, 4));
            t = fmaxf(t, __shfl_xor(t, 8));
            const float mn = fmaxf(m[r], t);
            al[r] = __expf(m[r] - mn);
            m[r] = mn;
        }

        float ps[4] = {0.f, 0.f, 0.f, 0.f};
        #pragma unroll
        for (int n = 0; n < 4; ++n) {
            #pragma unroll
            for (int r = 0; r < 4; ++r) {
                const float p = __expf(s[n][r] - m[r]);
                ps[r] += p;
                short ph, pl;
                bsplit(p, ph, pl);
                const int row = w * 16 + lg * 4 + r;
                const int key = n * 16 + ln;
                P_hi[swz(row, key)] = ph;
                P_lo[swz(row, key)] = pl;
            }
        }
        #pragma unroll
        for (int r = 0; r < 4; ++r) {
            float t = ps[r];
            t += __shfl_xor(t, 1);
            t += __shfl_xor(t, 2);
            t += __shfl_xor(t, 4);
            t += __shfl_xor(t, 8);
            lsum[r] = lsum[r] * al[r] + t;
            acc[0][r] *= al[r];
            acc[1][r] *= al[r];
            acc[2][r] *= al[r];
            acc[3][r] *= al[r];
        }

        bf16x8 pa_hi[2], pa_lo[2];
        #pragma unroll
        for (int ks = 0; ks < 2; ++ks) {
            pa_hi[ks] = *(const bf16x8*)&P_hi[swz(w * 16 + ln, ks * 32 + lg * 8)];
            pa_lo[ks] = *(const bf16x8*)&P_lo[swz(w * 16 + ln, ks * 32 + lg * 8)];
        }
        #pragma unroll
        for (int n = 0; n < 4; ++n) {
            #pragma unroll
            for (int ks = 0; ks < 2; ++ks) {
                bf16x8 vb_hi = *(const bf16x8*)&Vt_hi[swz(n * 16 + ln, ks * 32 + lg * 8)];
                bf16x8 vb_lo = *(const bf16x8*)&Vt_lo[swz(n * 16 + ln, ks * 32 + lg * 8)];
                acc[n] = MFMA16(pa_hi[ks], vb_hi, acc[n]);
                acc[n] = MFMA16(pa_lo[ks], vb_hi, acc[n]);
                acc[n] = MFMA16(pa_hi[ks], vb_lo, acc[n]);
            }
        }
    }

    #pragma unroll
    for (int r = 0; r < 4; ++r) {
        const float inv = 1.f / lsum[r];
        const int q = q0 + w * 16 + lg * 4 + r;
        const size_t idx = ((size_t)(b * L) + q) * D + h * 64;
        #pragma unroll
        for (int n = 0; n < 4; ++n) {
            short hh, ll;
            bsplit(acc[n][r] * inv, hh, ll);
            ctxh[idx + n * 16 + ln] = (u16)hh;
            ctxl[idx + n * 16 + ln] = (u16)ll;
        }
    }
}

extern "C" void kernel_launch(void* const* d_in, const int* in_sizes, int n_in,
                              void* d_out, int out_size, void* d_ws, size_t ws_size,
                              hipStream_t stream) {
    const float* x     = (const float*)d_in[0];
    const float* W_qkv = (const float*)d_in[1];
    const float* b_qkv = (const float*)d_in[2];
    const float* W_lin = (const float*)d_in[3];
    const float* b_lin = (const float*)d_in[4];
    float* out = (float*)d_out;

    const int M = 8192, D = 1024, D3 = 3072;

    char* ws = (char*)d_ws;
    float* qkvbuf = (float*)ws;                               // [0, 96M)
    u16* wlh  = (u16*)ws;                                     // [0, 2M)   after attn
    u16* wll  = (u16*)(ws + (size_t)2 * 1024 * 1024);         // [2M, 4M)  after attn
    const size_t CTX0 = (size_t)M * D3 * 4;                   // 96M
    u16* wqh  = (u16*)(ws + CTX0);                            // [96M,102M) pre-attn
    u16* wql  = (u16*)(ws + CTX0 + (size_t)D3 * D * 2);       // [102M,108M) pre-attn
    u16* ctxh = (u16*)(ws + CTX0);                            // [96M,112M)
    u16* ctxl = (u16*)(ws + CTX0 + (size_t)M * D * 2);        // [112M,128M)

    // 1) W_qkv -> transposed split (aliases ctx region; consumed by GEMM1)
    wsplit_t<<<dim3(D3 / 64, D / 64), 256, 0, stream>>>(W_qkv, wqh, wql, D, D3);
    // 2) qkv = x @ W_qkv + b_qkv
    gemm_split<true><<<dim3(D3 / 128, M / 128), 256, 0, stream>>>(
        x, nullptr, nullptr, wqh, wql, b_qkv, qkvbuf, M, D3, D);
    // 3) attention -> ctx hi/lo (clobbers wqh/wql, fine)
    attn_mfma<<<dim3(32, 16, 4), 256, 0, stream>>>(qkvbuf, ctxh, ctxl);
    // 4) W_lin -> transposed split (into dead qkv region)
    wsplit_t<<<dim3(D / 64, D / 64), 256, 0, stream>>>(W_lin, wlh, wll, D, D);
    // 5) out = ctx @ W_lin + b_lin
    gemm_split<false><<<dim3(D / 128, M / 128), 256, 0, stream>>>(
        nullptr, ctxh, ctxl, wlh, wll, b_lin, out, M, D, D);
}

// Round 7
// 659.156 us; speedup vs baseline: 3.3283x; 1.2162x over previous
//
#include <hip/hip_runtime.h>
#include <math.h>
#include <stdint.h>

// ---------------------------------------------------------------------------
// B=4, L=2048, D=1024, H=16, Hd=64
// 1) wsplit_t: W_qkv -> W^T bf16 hi/lo
// 2) gemm_split<true,true>: qkv GEMM; epilogue writes Q (hi/lo, scaled) and
//    K / V^T as PRE-SWIZZLED tile images so attention stages them with pure
//    linear global_load_lds (no VALU, no LDS write conflicts).
// 3) attn_mfma: causal flash attn (bf16-split MFMA), ctx -> hi/lo
// 4) wsplit_t: W_lin -> W^T bf16 hi/lo (into dead Q region)
// 5) gemm_split<false,false>: out = ctx @ W_lin + b
//
// ws layout (128 MiB):
//   [0,96M)   Qh Ql Kh Kl Vth Vtl (16M each); after attn first 4M = Wlin^T
//   [96M,128M) pre-GEMM1: Wqkv^T hi/lo (12M); after attn: ctx hi/lo (16M+16M)
// ---------------------------------------------------------------------------

typedef __attribute__((ext_vector_type(8))) short bf16x8;
typedef __attribute__((ext_vector_type(4))) float f32x4;
typedef unsigned short u16;

#define MFMA16(a, b, c) __builtin_amdgcn_mfma_f32_16x16x32_bf16(a, b, c, 0, 0, 0)

// Split fp32 into bf16 hi + bf16 lo (x ~= hi + lo, residual ~2^-16 rel)
__device__ __forceinline__ void bsplit(float x, short& hi, short& lo) {
    unsigned u = __builtin_bit_cast(unsigned, x);
    unsigned hu = u & 0xffff0000u;
    hi = (short)(hu >> 16);
    float r = x - __builtin_bit_cast(float, hu);
    lo = (short)(__builtin_bit_cast(unsigned, r) >> 16);
}

// async global->LDS, 16B per lane
__device__ __forceinline__ void gload16(const void* g, void* l) {
    __builtin_amdgcn_global_load_lds(
        (const __attribute__((address_space(1))) void*)g,
        (__attribute__((address_space(3))) void*)l, 16, 0, 0);
}

// XOR swizzle for 64x64 bf16 tiles (short-index bits 3-5 ^= row&7).
// Permutes 16B units; keeps b128 alignment; fragment reads <=2-way.
__device__ __forceinline__ int swz(int row, int col) {
    return ((row << 6) | col) ^ ((row & 7) << 3);
}

// ---------------------------------------------------------------------------
// Transpose + split: W[K][N] f32 -> outh/outl[N][K] bf16
// ---------------------------------------------------------------------------
__global__ __launch_bounds__(256) void wsplit_t(
    const float* __restrict__ W, u16* __restrict__ outh, u16* __restrict__ outl,
    int K, int N)
{
    __shared__ float t[64][68];
    const int n0 = blockIdx.x * 64, k0 = blockIdx.y * 64;
    const int tid = threadIdx.x;
    const int r = tid >> 4, c4 = (tid & 15) * 4;
    #pragma unroll
    for (int i = 0; i < 4; ++i) {
        const int rr = r + i * 16;
        float4 v = *(const float4*)&W[(size_t)(k0 + rr) * N + n0 + c4];
        t[rr][c4 + 0] = v.x; t[rr][c4 + 1] = v.y;
        t[rr][c4 + 2] = v.z; t[rr][c4 + 3] = v.w;
    }
    __syncthreads();
    #pragma unroll
    for (int i = 0; i < 4; ++i) {
        const int nr = r + i * 16;
        unsigned h01 = 0, h23 = 0, l01 = 0, l23 = 0;
        {
            short hh, ll;
            bsplit(t[c4 + 0][nr], hh, ll); h01 |= (unsigned)(u16)hh; l01 |= (unsigned)(u16)ll;
            bsplit(t[c4 + 1][nr], hh, ll); h01 |= (unsigned)(u16)hh << 16; l01 |= (unsigned)(u16)ll << 16;
            bsplit(t[c4 + 2][nr], hh, ll); h23 |= (unsigned)(u16)hh; l23 |= (unsigned)(u16)ll;
            bsplit(t[c4 + 3][nr], hh, ll); h23 |= (unsigned)(u16)hh << 16; l23 |= (unsigned)(u16)ll << 16;
        }
        *(uint2*)&outh[(size_t)(n0 + nr) * K + k0 + c4] = make_uint2(h01, h23);
        *(uint2*)&outl[(size_t)(n0 + nr) * K + k0 + c4] = make_uint2(l01, l23);
    }
}

// ---------------------------------------------------------------------------
// bf16-split MFMA GEMM. 128x128 tile, BK=32, 4 waves (2x2 of 64x64).
// QKVOUT epilogue: N=3072 cols -> q (scaled+split, [b][h][l][64]) /
// k (split, swizzled tile image) / v (split, transposed swizzled tile image).
// col0 is 128-aligned so the q/k/v branch is block-uniform.
// ---------------------------------------------------------------------------
template<bool AF32, bool QKVOUT>
__global__ __launch_bounds__(256) void gemm_split(
    const float* __restrict__ Af,
    const u16* __restrict__ Ah, const u16* __restrict__ Al,
    const u16* __restrict__ Bth, const u16* __restrict__ Btl,
    const float* __restrict__ bias, float* __restrict__ C,
    u16* __restrict__ qh, u16* __restrict__ ql,
    u16* __restrict__ kh, u16* __restrict__ kl,
    u16* __restrict__ vth, u16* __restrict__ vtl,
    int M, int N, int K)
{
    __shared__ u16 sAh[128 * 32], sAl[128 * 32], sBh[128 * 32], sBl[128 * 32];

    const int tid  = threadIdx.x;
    const int lane = tid & 63;
    const int ln   = lane & 15;
    const int lg   = lane >> 4;
    const int w    = tid >> 6;
    const int wr   = (w >> 1) * 64;
    const int wc   = (w & 1) * 64;
    const int row0 = blockIdx.y * 128;
    const int col0 = blockIdx.x * 128;

    f32x4 acc[4][4];
    #pragma unroll
    for (int mi = 0; mi < 4; ++mi)
        #pragma unroll
        for (int ni = 0; ni < 4; ++ni)
            acc[mi][ni] = (f32x4){0.f, 0.f, 0.f, 0.f};

    for (int kt = 0; kt < K; kt += 32) {
        __syncthreads();
        #pragma unroll
        for (int rd = 0; rd < 2; ++rd) {
            const int ch = tid + rd * 256;
            const int r = ch >> 2, kc = (ch & 3) * 8;
            gload16(Bth + (size_t)(col0 + r) * K + kt + kc, &sBh[ch * 8]);
            gload16(Btl + (size_t)(col0 + r) * K + kt + kc, &sBl[ch * 8]);
            if constexpr (!AF32) {
                gload16(Ah + (size_t)(row0 + r) * K + kt + kc, &sAh[ch * 8]);
                gload16(Al + (size_t)(row0 + r) * K + kt + kc, &sAl[ch * 8]);
            }
        }
        if constexpr (AF32) {
            const int r = tid >> 1, ks = (tid & 1) * 16;
            const float* ap = Af + (size_t)(row0 + r) * K + kt + ks;
            float v[16];
            *(float4*)&v[0]  = *(const float4*)(ap + 0);
            *(float4*)&v[4]  = *(const float4*)(ap + 4);
            *(float4*)&v[8]  = *(const float4*)(ap + 8);
            *(float4*)&v[12] = *(const float4*)(ap + 12);
            bf16x8 h0, h1, l0, l1;
            #pragma unroll
            for (int e = 0; e < 8; ++e) {
                short hh, ll;
                bsplit(v[e], hh, ll);     h0[e] = hh; l0[e] = ll;
                bsplit(v[8 + e], hh, ll); h1[e] = hh; l1[e] = ll;
            }
            *(bf16x8*)&sAh[r * 32 + ks]     = h0;
            *(bf16x8*)&sAh[r * 32 + ks + 8] = h1;
            *(bf16x8*)&sAl[r * 32 + ks]     = l0;
            *(bf16x8*)&sAl[r * 32 + ks + 8] = l1;
        }
        __syncthreads();

        bf16x8 a_h[4], a_l[4], b_h[4], b_l[4];
        #pragma unroll
        for (int mi = 0; mi < 4; ++mi) {
            const int o = (wr + mi * 16 + ln) * 32 + lg * 8;
            a_h[mi] = *(const bf16x8*)&sAh[o];
            a_l[mi] = *(const bf16x8*)&sAl[o];
        }
        #pragma unroll
        for (int ni = 0; ni < 4; ++ni) {
            const int o = (wc + ni * 16 + ln) * 32 + lg * 8;
            b_h[ni] = *(const bf16x8*)&sBh[o];
            b_l[ni] = *(const bf16x8*)&sBl[o];
        }
        #pragma unroll
        for (int mi = 0; mi < 4; ++mi)
            #pragma unroll
            for (int ni = 0; ni < 4; ++ni) {
                acc[mi][ni] = MFMA16(a_h[mi], b_h[ni], acc[mi][ni]);
                acc[mi][ni] = MFMA16(a_l[mi], b_h[ni], acc[mi][ni]);
                acc[mi][ni] = MFMA16(a_h[mi], b_l[ni], acc[mi][ni]);
            }
    }

    if constexpr (QKVOUT) {
        const int t = col0 >> 10;             // 0=q 1=k 2=v, block-uniform
        #pragma unroll
        for (int ni = 0; ni < 4; ++ni) {
            const int col = col0 + wc + ni * 16 + ln;
            const int hh  = (col & 1023) >> 6;
            const int d   = col & 63;
            const float bi = bias[col];
            const size_t hb = (size_t)((row0 >> 11) * 16 + hh);   // batch*16+head
            #pragma unroll
            for (int mi = 0; mi < 4; ++mi) {
                const int l0g = (row0 + wr + mi * 16 + lg * 4) & 2047;
                if (t == 0) {
                    #pragma unroll
                    for (int j = 0; j < 4; ++j) {
                        short hi_, lo_;
                        bsplit((acc[mi][ni][j] + bi) * 0.125f, hi_, lo_);
                        const size_t p = (hb * 2048 + l0g + j) * 64 + d;
                        qh[p] = (u16)hi_; ql[p] = (u16)lo_;
                    }
                } else if (t == 1) {
                    #pragma unroll
                    for (int j = 0; j < 4; ++j) {
                        short hi_, lo_;
                        bsplit(acc[mi][ni][j] + bi, hi_, lo_);
                        const int l = l0g + j;
                        const size_t p = (hb * 32 + (l >> 6)) * 4096 + swz(l & 63, d);
                        kh[p] = (u16)hi_; kl[p] = (u16)lo_;
                    }
                } else {
                    // V^T tile image: 4 consecutive l share one 8B store
                    unsigned h01 = 0, h23 = 0, l01 = 0, l23 = 0;
                    #pragma unroll
                    for (int j = 0; j < 4; ++j) {
                        short hi_, lo_;
                        bsplit(acc[mi][ni][j] + bi, hi_, lo_);
                        if (j < 2) {
                            h01 |= (unsigned)(u16)hi_ << (16 * j);
                            l01 |= (unsigned)(u16)lo_ << (16 * j);
                        } else {
                            h23 |= (unsigned)(u16)hi_ << (16 * (j - 2));
                            l23 |= (unsigned)(u16)lo_ << (16 * (j - 2));
                        }
                    }
                    const size_t p = (hb * 32 + (l0g >> 6)) * 4096 + swz(d, l0g & 63);
                    *(uint2*)&vth[p] = make_uint2(h01, h23);
                    *(uint2*)&vtl[p] = make_uint2(l01, l23);
                }
            }
        }
    } else {
        #pragma unroll
        for (int ni = 0; ni < 4; ++ni) {
            const int col = col0 + wc + ni * 16 + ln;
            const float bi = bias[col];
            #pragma unroll
            for (int mi = 0; mi < 4; ++mi)
                #pragma unroll
                for (int j = 0; j < 4; ++j) {
                    const int row = row0 + wr + mi * 16 + lg * 4 + j;
                    C[(size_t)row * N + col] = acc[mi][ni][j] + bi;
                }
        }
    }
}

// ---------------------------------------------------------------------------
// Flash attention, bf16-split MFMA. K/V pre-split + pre-swizzled in global;
// staging is pure linear global_load_lds. Q pre-split/scaled, loaded to regs.
// ---------------------------------------------------------------------------
__global__ __launch_bounds__(256) void attn_mfma(
    const u16* __restrict__ Qh, const u16* __restrict__ Ql,
    const u16* __restrict__ Kh, const u16* __restrict__ Kl,
    const u16* __restrict__ Vth, const u16* __restrict__ Vtl,
    u16* __restrict__ ctxh, u16* __restrict__ ctxl)
{
    const int L = 2048, D = 1024;
    const int qt = blockIdx.x;
    const int h  = blockIdx.y;
    const int b  = blockIdx.z;
    const int q0 = qt * 64;

    __shared__ u16 sKh[4096], sKl[4096], sVh[4096], sVl[4096];
    __shared__ u16 P_hi[4096], P_lo[4096];

    const int tid = threadIdx.x;
    const int w = tid >> 6;
    const int lane = tid & 63;
    const int ln = lane & 15;
    const int lg = lane >> 4;
    const size_t hb = (size_t)(b * 16 + h);

    // Q fragments (scale+bias already folded by GEMM1 epilogue)
    bf16x8 qa_hi[2], qa_lo[2];
    {
        const size_t qoff = (hb * 2048 + q0 + w * 16 + ln) * 64 + lg * 8;
        qa_hi[0] = *(const bf16x8*)(Qh + qoff);
        qa_hi[1] = *(const bf16x8*)(Qh + qoff + 32);
        qa_lo[0] = *(const bf16x8*)(Ql + qoff);
        qa_lo[1] = *(const bf16x8*)(Ql + qoff + 32);
    }

    float m[4], lsum[4];
    f32x4 acc[4];
    #pragma unroll
    for (int r = 0; r < 4; ++r) { m[r] = -INFINITY; lsum[r] = 0.f; }
    #pragma unroll
    for (int n = 0; n < 4; ++n) acc[n] = (f32x4){0.f, 0.f, 0.f, 0.f};

    for (int kt = 0; kt <= qt; ++kt) {
        __syncthreads();   // previous tile's K/V reads done before overwrite

        // Linear staging of pre-swizzled tile images: 2 chunks/array/thread.
        {
            const size_t tb = (hb * 32 + kt) * 4096;
            const int c0 = tid * 8, c1 = (tid + 256) * 8;
            gload16(Kh  + tb + c0, &sKh[c0]);
            gload16(Kh  + tb + c1, &sKh[c1]);
            gload16(Kl  + tb + c0, &sKl[c0]);
            gload16(Kl  + tb + c1, &sKl[c1]);
            gload16(Vth + tb + c0, &sVh[c0]);
            gload16(Vth + tb + c1, &sVh[c1]);
            gload16(Vtl + tb + c0, &sVl[c0]);
            gload16(Vtl + tb + c1, &sVl[c1]);
        }
        __syncthreads();   // barrier drains vmcnt -> LDS image complete

        // S = Q K^T
        f32x4 s[4];
        #pragma unroll
        for (int n = 0; n < 4; ++n) {
            f32x4 sa = (f32x4){0.f, 0.f, 0.f, 0.f};
            #pragma unroll
            for (int ks = 0; ks < 2; ++ks) {
                bf16x8 kb_hi = *(const bf16x8*)&sKh[swz(n * 16 + ln, ks * 32 + lg * 8)];
                bf16x8 kb_lo = *(const bf16x8*)&sKl[swz(n * 16 + ln, ks * 32 + lg * 8)];
                sa = MFMA16(qa_hi[ks], kb_hi, sa);
                sa = MFMA16(qa_lo[ks], kb_hi, sa);
                sa = MFMA16(qa_hi[ks], kb_lo, sa);
            }
            s[n] = sa;
        }

        if (kt == qt) {    // causal mask on the diagonal tile
            #pragma unroll
            for (int n = 0; n < 4; ++n)
                #pragma unroll
                for (int r = 0; r < 4; ++r) {
                    const int key = n * 16 + ln;
                    const int qr  = w * 16 + lg * 4 + r;
                    if (key > qr) s[n][r] = -INFINITY;
                }
        }

        // Online softmax (row stats across the 16 lanes sharing lg)
        float al[4];
        #pragma unroll
        for (int r = 0; r < 4; ++r) {
            float t = fmaxf(fmaxf(s[0][r], s[1][r]), fmaxf(s[2][r], s[3][r]));
            t = fmaxf(t, __shfl_xor(t, 1));
            t = fmaxf(t, __shfl_xor(t, 2));
            t = fmaxf(t, __shfl_xor(t, 4));
            t = fmaxf(t, __shfl_xor(t, 8));
            const float mn = fmaxf(m[r], t);
            al[r] = __expf(m[r] - mn);
            m[r] = mn;
        }

        float ps[4] = {0.f, 0.f, 0.f, 0.f};
        #pragma unroll
        for (int n = 0; n < 4; ++n) {
            #pragma unroll
            for (int r = 0; r < 4; ++r) {
                const float p = __expf(s[n][r] - m[r]);
                ps[r] += p;
                short ph, pl;
                bsplit(p, ph, pl);
                const int row = w * 16 + lg * 4 + r;
                const int key = n * 16 + ln;
                P_hi[swz(row, key)] = (u16)ph;
                P_lo[swz(row, key)] = (u16)pl;
            }
        }
        #pragma unroll
        for (int r = 0; r < 4; ++r) {
            float t = ps[r];
            t += __shfl_xor(t, 1);
            t += __shfl_xor(t, 2);
            t += __shfl_xor(t, 4);
            t += __shfl_xor(t, 8);
            lsum[r] = lsum[r] * al[r] + t;
            acc[0][r] *= al[r];
            acc[1][r] *= al[r];
            acc[2][r] *= al[r];
            acc[3][r] *= al[r];
        }

        // PV (P round-trip is wave-local; no barrier needed)
        bf16x8 pa_hi[2], pa_lo[2];
        #pragma unroll
        for (int ks = 0; ks < 2; ++ks) {
            pa_hi[ks] = *(const bf16x8*)&P_hi[swz(w * 16 + ln, ks * 32 + lg * 8)];
            pa_lo[ks] = *(const bf16x8*)&P_lo[swz(w * 16 + ln, ks * 32 + lg * 8)];
        }
        #pragma unroll
        for (int n = 0; n < 4; ++n) {
            #pragma unroll
            for (int ks = 0; ks < 2; ++ks) {
                bf16x8 vb_hi = *(const bf16x8*)&sVh[swz(n * 16 + ln, ks * 32 + lg * 8)];
                bf16x8 vb_lo = *(const bf16x8*)&sVl[swz(n * 16 + ln, ks * 32 + lg * 8)];
                acc[n] = MFMA16(pa_hi[ks], vb_hi, acc[n]);
                acc[n] = MFMA16(pa_lo[ks], vb_hi, acc[n]);
                acc[n] = MFMA16(pa_hi[ks], vb_lo, acc[n]);
            }
        }
    }

    #pragma unroll
    for (int r = 0; r < 4; ++r) {
        const float inv = 1.f / lsum[r];
        const int q = q0 + w * 16 + lg * 4 + r;
        const size_t idx = ((size_t)(b * L) + q) * D + h * 64;
        #pragma unroll
        for (int n = 0; n < 4; ++n) {
            short hh, ll;
            bsplit(acc[n][r] * inv, hh, ll);
            ctxh[idx + n * 16 + ln] = (u16)hh;
            ctxl[idx + n * 16 + ln] = (u16)ll;
        }
    }
}

extern "C" void kernel_launch(void* const* d_in, const int* in_sizes, int n_in,
                              void* d_out, int out_size, void* d_ws, size_t ws_size,
                              hipStream_t stream) {
    const float* x     = (const float*)d_in[0];
    const float* W_qkv = (const float*)d_in[1];
    const float* b_qkv = (const float*)d_in[2];
    const float* W_lin = (const float*)d_in[3];
    const float* b_lin = (const float*)d_in[4];
    float* out = (float*)d_out;

    const int M = 8192, D = 1024, D3 = 3072;
    const size_t MB = 1024 * 1024;

    char* ws = (char*)d_ws;
    u16* Qh  = (u16*)(ws + 0 * MB);
    u16* Ql  = (u16*)(ws + 16 * MB);
    u16* Kh  = (u16*)(ws + 32 * MB);
    u16* Kl  = (u16*)(ws + 48 * MB);
    u16* Vth = (u16*)(ws + 64 * MB);
    u16* Vtl = (u16*)(ws + 80 * MB);
    u16* wqh = (u16*)(ws + 96 * MB);    // pre-attn only (6M)
    u16* wql = (u16*)(ws + 102 * MB);   // pre-attn only (6M)
    u16* ctxh = (u16*)(ws + 96 * MB);   // post-attn (16M)
    u16* ctxl = (u16*)(ws + 112 * MB);  // post-attn (16M)
    u16* wlh = (u16*)(ws + 0 * MB);     // post-attn (2M, dead Q region)
    u16* wll = (u16*)(ws + 2 * MB);     // post-attn (2M)

    // 1) W_qkv -> transposed split
    wsplit_t<<<dim3(D3 / 64, D / 64), 256, 0, stream>>>(W_qkv, wqh, wql, D, D3);
    // 2) QKV GEMM, epilogue -> attention-ready Q/K/V^T layouts
    gemm_split<true, true><<<dim3(D3 / 128, M / 128), 256, 0, stream>>>(
        x, nullptr, nullptr, wqh, wql, b_qkv, nullptr,
        Qh, Ql, Kh, Kl, Vth, Vtl, M, D3, D);
    // 3) attention -> ctx hi/lo (clobbers wq region: dead)
    attn_mfma<<<dim3(32, 16, 4), 256, 0, stream>>>(
        Qh, Ql, Kh, Kl, Vth, Vtl, ctxh, ctxl);
    // 4) W_lin -> transposed split (into dead Q region)
    wsplit_t<<<dim3(D / 64, D / 64), 256, 0, stream>>>(W_lin, wlh, wll, D, D);
    // 5) out = ctx @ W_lin + b_lin
    gemm_split<false, false><<<dim3(D / 128, M / 128), 256, 0, stream>>>(
        nullptr, ctxh, ctxl, wlh, wll, b_lin, out,
        nullptr, nullptr, nullptr, nullptr, nullptr, nullptr, M, D, D);
}